// Round 5
// baseline (3489.154 us; speedup 1.0000x reference)
//
#include <hip/hip_runtime.h>
#include <hip/hip_bf16.h>
#include <math.h>

#define NUM_HEADS 12
#define N_TOK 197
#define C_DIM 768
#define B_SZ 64
#define M_ROWS (B_SZ * N_TOK)     /* 12608 = 32*394 */
#define QKV_COLS (3 * C_DIM)      /* 2304  */
#define NN (N_TOK * N_TOK)        /* 38809 */

typedef unsigned long long u64;

// ---------------------------------------------------------------------------
// f64-accumulate GEMM: C[M,N] = A[M,K] @ B[N,K]^T (+bias), fp32 in/out.
// 32x32 tile, 2x2 per thread, exact f64 products (fp32->f64 casts are exact).
// M%32==0, N%32==0, K%32==0 for our shapes -> no guards.
// ---------------------------------------------------------------------------
template<bool ADD_BIAS>
__global__ __launch_bounds__(256) void gemm_f64(
    const float* __restrict__ A, const float* __restrict__ B,
    const float* __restrict__ bias, float* __restrict__ C,
    int M, int N, int K)
{
    __shared__ float As[32][33];
    __shared__ float Bs[32][33];
    const int t = threadIdx.x;
    const int tile_m = blockIdx.y * 32, tile_n = blockIdx.x * 32;
    const int ty = t >> 4, tx = t & 15;
    const int r0 = ty * 2, c0 = tx * 2;
    double acc00 = 0, acc01 = 0, acc10 = 0, acc11 = 0;

    for (int k0 = 0; k0 < K; k0 += 32) {
        __syncthreads();
#pragma unroll
        for (int s = 0; s < 4; ++s) {
            int idx = s * 256 + t;
            int row = idx >> 5, col = idx & 31;
            As[row][col] = A[(size_t)(tile_m + row) * K + k0 + col];
            Bs[row][col] = B[(size_t)(tile_n + row) * K + k0 + col];
        }
        __syncthreads();
#pragma unroll
        for (int kk = 0; kk < 32; ++kk) {
            double a0 = (double)As[r0][kk], a1 = (double)As[r0 + 1][kk];
            double b0 = (double)Bs[c0][kk], b1 = (double)Bs[c0 + 1][kk];
            acc00 = fma(a0, b0, acc00);
            acc01 = fma(a0, b1, acc01);
            acc10 = fma(a1, b0, acc10);
            acc11 = fma(a1, b1, acc11);
        }
    }
    double bb0 = ADD_BIAS ? (double)bias[tile_n + c0] : 0.0;
    double bb1 = ADD_BIAS ? (double)bias[tile_n + c0 + 1] : 0.0;
    C[(size_t)(tile_m + r0) * N + tile_n + c0]         = (float)(acc00 + bb0);
    C[(size_t)(tile_m + r0) * N + tile_n + c0 + 1]     = (float)(acc01 + bb1);
    C[(size_t)(tile_m + r0 + 1) * N + tile_n + c0]     = (float)(acc10 + bb0);
    C[(size_t)(tile_m + r0 + 1) * N + tile_n + c0 + 1] = (float)(acc11 + bb1);
}

// ---------------------------------------------------------------------------
// Per-(b,h): s_q, s_k (f64 means of |.|), svd[d] = 127/(max_n|v|+1e-6) in f64,
// packed sign bits of q and k (sign of fp32-rounded q == sign of f64 q).
// ---------------------------------------------------------------------------
__global__ __launch_bounds__(256) void quant_stats_f64(
    const float* __restrict__ qkv, double* __restrict__ sq, double* __restrict__ sk,
    u64* __restrict__ qbits, u64* __restrict__ kbits, double* __restrict__ svd)
{
    const int bh = blockIdx.x;
    const int b = bh / NUM_HEADS, h = bh % NUM_HEADS;
    const int t = threadIdx.x;
    const size_t base = (size_t)b * N_TOK * QKV_COLS + h * 64;
    __shared__ double red[256];
    __shared__ float redf[256];

    const int d = t & 63;
    double aq = 0.0, ak = 0.0;
    for (int i = t; i < N_TOK * 64; i += 256) {
        int n = i >> 6;
        size_t off = base + (size_t)n * QKV_COLS + d;
        aq += (double)fabsf(qkv[off]);
        ak += (double)fabsf(qkv[off + C_DIM]);
    }
    red[t] = aq; __syncthreads();
    for (int s = 128; s > 0; s >>= 1) { if (t < s) red[t] += red[t + s]; __syncthreads(); }
    if (t == 0) sq[bh] = red[0] / 12608.0;
    __syncthreads();
    red[t] = ak; __syncthreads();
    for (int s = 128; s > 0; s >>= 1) { if (t < s) red[t] += red[t + s]; __syncthreads(); }
    if (t == 0) sk[bh] = red[0] / 12608.0;
    __syncthreads();

    float vm = 0.f;
    for (int n = (t >> 6); n < N_TOK; n += 4)
        vm = fmaxf(vm, fabsf(qkv[base + (size_t)n * QKV_COLS + 2 * C_DIM + d]));
    redf[t] = vm; __syncthreads();
    if (t < 64) {
        float m4 = fmaxf(fmaxf(redf[t], redf[t + 64]), fmaxf(redf[t + 128], redf[t + 192]));
        svd[bh * 64 + t] = 127.0 / ((double)m4 + 1e-6);
    }

    const int wave = t >> 6, lane = t & 63;
    for (int n = wave; n < N_TOK; n += 4) {
        size_t off = base + (size_t)n * QKV_COLS + lane;
        u64 bq = __ballot(qkv[off] >= 0.f);
        u64 bk = __ballot(qkv[off + C_DIM] >= 0.f);
        if (lane == 0) { qbits[bh * N_TOK + n] = bq; kbits[bh * N_TOK + n] = bk; }
    }
}

// int64-vs-int32 probe for rel_index (kept from R4; proven int32 but harmless)
__global__ void detect_rel64(const int* __restrict__ rel, int* __restrict__ flag)
{
    __shared__ int nz;
    if (threadIdx.x == 0) nz = 0;
    __syncthreads();
    int local = 0;
    for (int i = threadIdx.x; i < NN / 2; i += 256)
        if (rel[2 * i + 1] != 0) local = 1;
    if (local) atomicOr(&nz, 1);
    __syncthreads();
    if (threadIdx.x == 0) flag[0] = (nz == 0) ? 1 : 0;
}

__global__ void build_bias(const float* __restrict__ rpb, const int* __restrict__ rel,
                           const int* __restrict__ flag, float* __restrict__ bias_f)
{
    int nm = blockIdx.x * 256 + threadIdx.x;
    int h = blockIdx.y;
    if (nm < NN) {
        int idx = flag[0] ? rel[2 * nm] : rel[nm];
        bias_f[(size_t)h * NN + nm] = rpb[idx * NUM_HEADS + h];
    }
}

// ---------------------------------------------------------------------------
// Fused attention, all decision arithmetic in f64:
// logits = sq*sk*0.125*(64-2*popc) + bias  -> softmax (f64 exp) -> quantize_p
// (f64 round decisions) -> P @ Vq (f64 accumulate). fp32 out.
// ---------------------------------------------------------------------------
__global__ __launch_bounds__(256) void attn_f64(
    const float* __restrict__ qkv, const double* __restrict__ sq, const double* __restrict__ sk,
    const u64* __restrict__ qbits, const u64* __restrict__ kbits,
    const double* __restrict__ svd, const float* __restrict__ bias_f,
    float* __restrict__ attn_out)
{
    const int bh = blockIdx.x;
    const int b = bh / NUM_HEADS, h = bh % NUM_HEADS;
    const int t = threadIdx.x;
    const int wave = t >> 6, lane = t & 63;

    __shared__ float vq[N_TOK * 64];   // 50.4 KB
    __shared__ u64 qb[N_TOK], kb[N_TOK];

    const size_t vbase = (size_t)b * N_TOK * QKV_COLS + 2 * C_DIM + h * 64;
    const double sv = svd[bh * 64 + (t & 63)];
    for (int i = t; i < N_TOK * 64; i += 256) {
        int n = i >> 6;
        double v = (double)qkv[vbase + (size_t)n * QKV_COLS + (i & 63)];
        vq[i] = (float)(rint(v * sv) / (sv + 1e-6));
    }
    for (int i = t; i < N_TOK; i += 256) {
        qb[i] = qbits[bh * N_TOK + i];
        kb[i] = kbits[bh * N_TOK + i];
    }
    __syncthreads();

    const double cf = sq[bh] * sk[bh] * 0.125;
    const float* bh_bias = bias_f + (size_t)h * NN;
    const double S = 1.0 / 255.0;

    for (int n = wave; n < N_TOK; n += 4) {
        const u64 qn = qb[n];
        int m0 = lane, m1 = 64 + lane, m2 = 128 + lane, m3 = 192 + lane;
        double l0 = cf * (double)(64 - 2 * (int)__popcll(qn ^ kb[m0])) + (double)bh_bias[n * N_TOK + m0];
        double l1 = cf * (double)(64 - 2 * (int)__popcll(qn ^ kb[m1])) + (double)bh_bias[n * N_TOK + m1];
        double l2 = cf * (double)(64 - 2 * (int)__popcll(qn ^ kb[m2])) + (double)bh_bias[n * N_TOK + m2];
        double l3 = -1e300;
        if (m3 < N_TOK)
            l3 = cf * (double)(64 - 2 * (int)__popcll(qn ^ kb[m3])) + (double)bh_bias[n * N_TOK + m3];

        double mx = fmax(fmax(l0, l1), fmax(l2, l3));
#pragma unroll
        for (int off = 32; off > 0; off >>= 1) mx = fmax(mx, __shfl_xor(mx, off, 64));
        double e0 = exp(l0 - mx), e1 = exp(l1 - mx), e2 = exp(l2 - mx);
        double e3 = (m3 < N_TOK) ? exp(l3 - mx) : 0.0;
        double sum = e0 + e1 + e2 + e3;
#pragma unroll
        for (int off = 32; off > 0; off >>= 1) sum += __shfl_xor(sum, off, 64);

        double p0 = S * fmin(rint((e0 / sum) / S), 255.0);
        double p1 = S * fmin(rint((e1 / sum) / S), 255.0);
        double p2 = S * fmin(rint((e2 / sum) / S), 255.0);
        double p3 = S * fmin(rint((e3 / sum) / S), 255.0);

        double acc = 0.0;
        const int d2 = lane;
#pragma unroll
        for (int mm = 0; mm < 64; ++mm) acc = fma(__shfl(p0, mm, 64), (double)vq[mm * 64 + d2], acc);
#pragma unroll
        for (int mm = 0; mm < 64; ++mm) acc = fma(__shfl(p1, mm, 64), (double)vq[(64 + mm) * 64 + d2], acc);
#pragma unroll
        for (int mm = 0; mm < 64; ++mm) acc = fma(__shfl(p2, mm, 64), (double)vq[(128 + mm) * 64 + d2], acc);
#pragma unroll
        for (int mm = 0; mm < 5; ++mm)  acc = fma(__shfl(p3, mm, 64), (double)vq[(192 + mm) * 64 + d2], acc);

        attn_out[((size_t)(b * N_TOK + n)) * C_DIM + h * 64 + d2] = (float)acc;
    }
}

// ---------------------------------------------------------------------------
extern "C" void kernel_launch(void* const* d_in, const int* in_sizes, int n_in,
                              void* d_out, int out_size, void* d_ws, size_t ws_size,
                              hipStream_t stream)
{
    const float* x      = (const float*)d_in[0];
    const float* w_qkv  = (const float*)d_in[1];
    const float* w_proj = (const float*)d_in[2];
    const float* b_proj = (const float*)d_in[3];
    const float* rpb    = (const float*)d_in[4];
    const int*   rel    = (const int*)d_in[5];
    float* out = (float*)d_out;

    char* ws = (char*)d_ws;
    float* qkv     = (float*)ws; ws += (size_t)M_ROWS * QKV_COLS * sizeof(float);  // 116.2 MB
    float* attn_o  = (float*)ws; ws += (size_t)M_ROWS * C_DIM * sizeof(float);     // 38.7 MB
    float* bias_f  = (float*)ws; ws += (size_t)NUM_HEADS * NN * sizeof(float);     // 1.86 MB
    double* sq     = (double*)ws; ws += 768 * sizeof(double);
    double* sk     = (double*)ws; ws += 768 * sizeof(double);
    double* svd    = (double*)ws; ws += 768 * 64 * sizeof(double);
    u64* qbits     = (u64*)ws;   ws += (size_t)768 * N_TOK * sizeof(u64);
    u64* kbits     = (u64*)ws;   ws += (size_t)768 * N_TOK * sizeof(u64);
    int* flag      = (int*)ws;   ws += 256;
    // total ~160 MB

    // 0) rel_index dtype probe
    detect_rel64<<<1, 256, 0, stream>>>(rel, flag);

    // 1) QKV = x @ w_qkv^T, f64-exact
    gemm_f64<false><<<dim3(QKV_COLS / 32, M_ROWS / 32), 256, 0, stream>>>(
        x, w_qkv, nullptr, qkv, M_ROWS, QKV_COLS, C_DIM);

    // 2) per-(b,h) scales (f64), sign bits, v column maxima
    quant_stats_f64<<<768, 256, 0, stream>>>(qkv, sq, sk, qbits, kbits, svd);

    // 3) fp32 bias table per head
    build_bias<<<dim3((NN + 255) / 256, NUM_HEADS), 256, 0, stream>>>(rpb, rel, flag, bias_f);

    // 4) fused attention, f64 decision arithmetic
    attn_f64<<<768, 256, 0, stream>>>(qkv, sq, sk, qbits, kbits, svd, bias_f, attn_o);

    // 5) out = attn_o @ w_proj^T + b_proj, f64-exact
    gemm_f64<true><<<dim3(C_DIM / 32, M_ROWS / 32), 256, 0, stream>>>(
        attn_o, w_proj, b_proj, out, M_ROWS, C_DIM, C_DIM);
}

// Round 7
// 1746.786 us; speedup vs baseline: 1.9975x; 1.9975x over previous
//
#include <hip/hip_runtime.h>
#include <hip/hip_bf16.h>
#include <math.h>

#define NUM_HEADS 12
#define N_TOK 197
#define C_DIM 768
#define B_SZ 64
#define M_ROWS (B_SZ * N_TOK)     /* 12608 */
#define QKV_COLS (3 * C_DIM)      /* 2304  */
#define NN (N_TOK * N_TOK)        /* 38809 */

typedef __hip_bfloat16 bf16;
typedef __attribute__((ext_vector_type(8))) short short8;
typedef __attribute__((ext_vector_type(4))) float floatx4;
typedef unsigned long long u64;

__device__ __forceinline__ void split2(float x, short& hi, short& lo) {
    bf16 h = __float2bfloat16(x);
    float hf = __bfloat162float(h);
    bf16 l = __float2bfloat16(x - hf);
    hi = __builtin_bit_cast(short, h);
    lo = __builtin_bit_cast(short, l);
}

__device__ __forceinline__ void split3(float x, short& s0, short& s1, short& s2) {
    bf16 h = __float2bfloat16(x);
    float r1 = x - __bfloat162float(h);          // exact
    bf16 m = __float2bfloat16(r1);
    float r2 = r1 - __bfloat162float(m);         // exact
    bf16 l = __float2bfloat16(r2);               // captures remaining bits
    s0 = __builtin_bit_cast(short, h);
    s1 = __builtin_bit_cast(short, m);
    s2 = __builtin_bit_cast(short, l);
}

// ---------------------------------------------------------------------------
// Near-fp32-exact GEMM: C = A @ B^T, fp32 in/out. 3-way bf16 split of both
// operands, 6 MFMA terms {00,01,02,10,11,20}; residual ~2.6e-7 abs — BELOW
// np.float32 sgemm's own noise (~4.6e-7). This is the flip-critical QKV path.
// 128x128 tile, BK=32, 4 waves. LDS 48 KB.
// ---------------------------------------------------------------------------
__global__ __launch_bounds__(256) void gemm_split6(
    const float* __restrict__ A, const float* __restrict__ B,
    float* __restrict__ C, int M, int N, int K)
{
    __shared__ short8 As[3][512];   // [split][kquad*128 + row]
    __shared__ short8 Bs[3][512];
    const int t = threadIdx.x;
    const int tile_m = blockIdx.y * 128;
    const int tile_n = blockIdx.x * 128;
    const int wave = t >> 6, lane = t & 63;
    const int quad = lane >> 4, mrow = lane & 15;
    const int wrow = (wave >> 1) * 64, wcol = (wave & 1) * 64;

    floatx4 acc[4][4];
#pragma unroll
    for (int i = 0; i < 4; ++i)
#pragma unroll
        for (int j = 0; j < 4; ++j) acc[i][j] = (floatx4){0.f, 0.f, 0.f, 0.f};

    for (int k0 = 0; k0 < K; k0 += 32) {
        __syncthreads();
#pragma unroll
        for (int s = 0; s < 2; ++s) {
            int idx = s * 256 + t;
            int row = idx >> 2, q = idx & 3;
            {
                int ga = tile_m + row;
                float4 a0 = {0.f, 0.f, 0.f, 0.f}, a1 = {0.f, 0.f, 0.f, 0.f};
                if (ga < M) {
                    const float* p = A + (size_t)ga * K + k0 + q * 8;
                    a0 = *(const float4*)p;
                    a1 = *(const float4*)(p + 4);
                }
                float xs[8] = {a0.x, a0.y, a0.z, a0.w, a1.x, a1.y, a1.z, a1.w};
                short8 v0, v1, v2;
#pragma unroll
                for (int e = 0; e < 8; ++e) {
                    short h, m, l; split3(xs[e], h, m, l);
                    v0[e] = h; v1[e] = m; v2[e] = l;
                }
                As[0][q * 128 + row] = v0;
                As[1][q * 128 + row] = v1;
                As[2][q * 128 + row] = v2;
            }
            {
                int gb = tile_n + row;
                float4 b0 = {0.f, 0.f, 0.f, 0.f}, b1 = {0.f, 0.f, 0.f, 0.f};
                if (gb < N) {
                    const float* p = B + (size_t)gb * K + k0 + q * 8;
                    b0 = *(const float4*)p;
                    b1 = *(const float4*)(p + 4);
                }
                float xs[8] = {b0.x, b0.y, b0.z, b0.w, b1.x, b1.y, b1.z, b1.w};
                short8 v0, v1, v2;
#pragma unroll
                for (int e = 0; e < 8; ++e) {
                    short h, m, l; split3(xs[e], h, m, l);
                    v0[e] = h; v1[e] = m; v2[e] = l;
                }
                Bs[0][q * 128 + row] = v0;
                Bs[1][q * 128 + row] = v1;
                Bs[2][q * 128 + row] = v2;
            }
        }
        __syncthreads();

        short8 af[4], bfr[4];
#pragma unroll
        for (int ta = 0; ta < 3; ++ta) {
#pragma unroll
            for (int i = 0; i < 4; ++i)
                af[i] = As[ta][quad * 128 + wrow + i * 16 + mrow];
            const int ntb = 3 - ta;   // (0:{0,1,2}) (1:{0,1}) (2:{0})
#pragma unroll
            for (int tb = 0; tb < 3; ++tb) {
                if (tb >= ntb) break;
#pragma unroll
                for (int j = 0; j < 4; ++j)
                    bfr[j] = Bs[tb][quad * 128 + wcol + j * 16 + mrow];
#pragma unroll
                for (int i = 0; i < 4; ++i)
#pragma unroll
                    for (int j = 0; j < 4; ++j)
                        acc[i][j] = __builtin_amdgcn_mfma_f32_16x16x32_bf16(af[i], bfr[j], acc[i][j], 0, 0, 0);
            }
        }
    }

#pragma unroll
    for (int i = 0; i < 4; ++i)
#pragma unroll
        for (int r = 0; r < 4; ++r) {
            int grow = tile_m + wrow + i * 16 + quad * 4 + r;
            if (grow < M)
#pragma unroll
                for (int j = 0; j < 4; ++j) {
                    int gcol = tile_n + wcol + j * 16 + mrow;
                    C[(size_t)grow * N + gcol] = acc[i][j][r];
                }
        }
}

// ---------------------------------------------------------------------------
// Proj GEMM: 2-way split, 4 terms (error ~4e-6 direct — feeds no discrete
// decisions; R2==R3 proved precision non-binding here). + bias.
// ---------------------------------------------------------------------------
__global__ __launch_bounds__(256) void gemm_split4_bias(
    const float* __restrict__ A, const float* __restrict__ B,
    const float* __restrict__ bias, float* __restrict__ C,
    int M, int N, int K)
{
    __shared__ short8 Ah[512], Al[512];
    __shared__ short8 Bh[512], Bl[512];
    const int t = threadIdx.x;
    const int tile_m = blockIdx.y * 128;
    const int tile_n = blockIdx.x * 128;
    const int wave = t >> 6, lane = t & 63;
    const int quad = lane >> 4, mrow = lane & 15;
    const int wrow = (wave >> 1) * 64, wcol = (wave & 1) * 64;

    floatx4 acc[4][4];
#pragma unroll
    for (int i = 0; i < 4; ++i)
#pragma unroll
        for (int j = 0; j < 4; ++j) acc[i][j] = (floatx4){0.f, 0.f, 0.f, 0.f};

    for (int k0 = 0; k0 < K; k0 += 32) {
        __syncthreads();
#pragma unroll
        for (int s = 0; s < 2; ++s) {
            int idx = s * 256 + t;
            int row = idx >> 2, q = idx & 3;
            {
                int ga = tile_m + row;
                float4 a0 = {0.f, 0.f, 0.f, 0.f}, a1 = {0.f, 0.f, 0.f, 0.f};
                if (ga < M) {
                    const float* p = A + (size_t)ga * K + k0 + q * 8;
                    a0 = *(const float4*)p; a1 = *(const float4*)(p + 4);
                }
                float xs[8] = {a0.x, a0.y, a0.z, a0.w, a1.x, a1.y, a1.z, a1.w};
                short8 hi, lo;
#pragma unroll
                for (int e = 0; e < 8; ++e) { short hh, ll; split2(xs[e], hh, ll); hi[e] = hh; lo[e] = ll; }
                Ah[q * 128 + row] = hi; Al[q * 128 + row] = lo;
            }
            {
                int gb = tile_n + row;
                float4 b0 = {0.f, 0.f, 0.f, 0.f}, b1 = {0.f, 0.f, 0.f, 0.f};
                if (gb < N) {
                    const float* p = B + (size_t)gb * K + k0 + q * 8;
                    b0 = *(const float4*)p; b1 = *(const float4*)(p + 4);
                }
                float xs[8] = {b0.x, b0.y, b0.z, b0.w, b1.x, b1.y, b1.z, b1.w};
                short8 hi, lo;
#pragma unroll
                for (int e = 0; e < 8; ++e) { short hh, ll; split2(xs[e], hh, ll); hi[e] = hh; lo[e] = ll; }
                Bh[q * 128 + row] = hi; Bl[q * 128 + row] = lo;
            }
        }
        __syncthreads();
        short8 ah[4], al[4], bh[4], bl[4];
#pragma unroll
        for (int i = 0; i < 4; ++i) {
            ah[i] = Ah[quad * 128 + wrow + i * 16 + mrow];
            al[i] = Al[quad * 128 + wrow + i * 16 + mrow];
        }
#pragma unroll
        for (int j = 0; j < 4; ++j) {
            bh[j] = Bh[quad * 128 + wcol + j * 16 + mrow];
            bl[j] = Bl[quad * 128 + wcol + j * 16 + mrow];
        }
#pragma unroll
        for (int i = 0; i < 4; ++i)
#pragma unroll
            for (int j = 0; j < 4; ++j) {
                acc[i][j] = __builtin_amdgcn_mfma_f32_16x16x32_bf16(al[i], bl[j], acc[i][j], 0, 0, 0);
                acc[i][j] = __builtin_amdgcn_mfma_f32_16x16x32_bf16(al[i], bh[j], acc[i][j], 0, 0, 0);
                acc[i][j] = __builtin_amdgcn_mfma_f32_16x16x32_bf16(ah[i], bl[j], acc[i][j], 0, 0, 0);
                acc[i][j] = __builtin_amdgcn_mfma_f32_16x16x32_bf16(ah[i], bh[j], acc[i][j], 0, 0, 0);
            }
    }

#pragma unroll
    for (int i = 0; i < 4; ++i)
#pragma unroll
        for (int r = 0; r < 4; ++r) {
            int grow = tile_m + wrow + i * 16 + quad * 4 + r;
            if (grow < M)
#pragma unroll
                for (int j = 0; j < 4; ++j) {
                    int gcol = tile_n + wcol + j * 16 + mrow;
                    C[(size_t)grow * N + gcol] = acc[i][j][r] + bias[gcol];
                }
        }
}

// ---------------------------------------------------------------------------
// Per-(b,h): s_q, s_k (f64 means), svd[d] = 127/(max|v|+1e-6) f64,
// packed q/k sign bits. (R5-proven f64 decision path.)
// ---------------------------------------------------------------------------
__global__ __launch_bounds__(256) void quant_stats_f64(
    const float* __restrict__ qkv, double* __restrict__ sq, double* __restrict__ sk,
    u64* __restrict__ qbits, u64* __restrict__ kbits, double* __restrict__ svd)
{
    const int bh = blockIdx.x;
    const int b = bh / NUM_HEADS, h = bh % NUM_HEADS;
    const int t = threadIdx.x;
    const size_t base = (size_t)b * N_TOK * QKV_COLS + h * 64;
    __shared__ double red[256];
    __shared__ float redf[256];

    const int d = t & 63;
    double aq = 0.0, ak = 0.0;
    for (int i = t; i < N_TOK * 64; i += 256) {
        int n = i >> 6;
        size_t off = base + (size_t)n * QKV_COLS + d;
        aq += (double)fabsf(qkv[off]);
        ak += (double)fabsf(qkv[off + C_DIM]);
    }
    red[t] = aq; __syncthreads();
    for (int s = 128; s > 0; s >>= 1) { if (t < s) red[t] += red[t + s]; __syncthreads(); }
    if (t == 0) sq[bh] = red[0] / 12608.0;
    __syncthreads();
    red[t] = ak; __syncthreads();
    for (int s = 128; s > 0; s >>= 1) { if (t < s) red[t] += red[t + s]; __syncthreads(); }
    if (t == 0) sk[bh] = red[0] / 12608.0;
    __syncthreads();

    float vm = 0.f;
    for (int n = (t >> 6); n < N_TOK; n += 4)
        vm = fmaxf(vm, fabsf(qkv[base + (size_t)n * QKV_COLS + 2 * C_DIM + d]));
    redf[t] = vm; __syncthreads();
    if (t < 64) {
        float m4 = fmaxf(fmaxf(redf[t], redf[t + 64]), fmaxf(redf[t + 128], redf[t + 192]));
        svd[bh * 64 + t] = 127.0 / ((double)m4 + 1e-6);
    }

    const int wave = t >> 6, lane = t & 63;
    for (int n = wave; n < N_TOK; n += 4) {
        size_t off = base + (size_t)n * QKV_COLS + lane;
        u64 bq = __ballot(qkv[off] >= 0.f);
        u64 bk = __ballot(qkv[off + C_DIM] >= 0.f);
        if (lane == 0) { qbits[bh * N_TOK + n] = bq; kbits[bh * N_TOK + n] = bk; }
    }
}

__global__ void detect_rel64(const int* __restrict__ rel, int* __restrict__ flag)
{
    __shared__ int nz;
    if (threadIdx.x == 0) nz = 0;
    __syncthreads();
    int local = 0;
    for (int i = threadIdx.x; i < NN / 2; i += 256)
        if (rel[2 * i + 1] != 0) local = 1;
    if (local) atomicOr(&nz, 1);
    __syncthreads();
    if (threadIdx.x == 0) flag[0] = (nz == 0) ? 1 : 0;
}

__global__ void build_bias(const float* __restrict__ rpb, const int* __restrict__ rel,
                           const int* __restrict__ flag, float* __restrict__ bias_f)
{
    int nm = blockIdx.x * 256 + threadIdx.x;
    int h = blockIdx.y;
    if (nm < NN) {
        int idx = flag[0] ? rel[2 * nm] : rel[nm];
        bias_f[(size_t)h * NN + nm] = rpb[idx * NUM_HEADS + h];
    }
}

// ---------------------------------------------------------------------------
// Fused attention, decision arithmetic in f64 (R5-proven, unchanged).
// ---------------------------------------------------------------------------
__global__ __launch_bounds__(256) void attn_f64(
    const float* __restrict__ qkv, const double* __restrict__ sq, const double* __restrict__ sk,
    const u64* __restrict__ qbits, const u64* __restrict__ kbits,
    const double* __restrict__ svd, const float* __restrict__ bias_f,
    float* __restrict__ attn_out)
{
    const int bh = blockIdx.x;
    const int b = bh / NUM_HEADS, h = bh % NUM_HEADS;
    const int t = threadIdx.x;
    const int wave = t >> 6, lane = t & 63;

    __shared__ float vq[N_TOK * 64];   // 50.4 KB
    __shared__ u64 qb[N_TOK], kb[N_TOK];

    const size_t vbase = (size_t)b * N_TOK * QKV_COLS + 2 * C_DIM + h * 64;
    const double sv = svd[bh * 64 + (t & 63)];
    for (int i = t; i < N_TOK * 64; i += 256) {
        int n = i >> 6;
        double v = (double)qkv[vbase + (size_t)n * QKV_COLS + (i & 63)];
        vq[i] = (float)(rint(v * sv) / (sv + 1e-6));
    }
    for (int i = t; i < N_TOK; i += 256) {
        qb[i] = qbits[bh * N_TOK + i];
        kb[i] = kbits[bh * N_TOK + i];
    }
    __syncthreads();

    const double cf = sq[bh] * sk[bh] * 0.125;
    const float* bh_bias = bias_f + (size_t)h * NN;
    const double S = 1.0 / 255.0;

    for (int n = wave; n < N_TOK; n += 4) {
        const u64 qn = qb[n];
        int m0 = lane, m1 = 64 + lane, m2 = 128 + lane, m3 = 192 + lane;
        double l0 = cf * (double)(64 - 2 * (int)__popcll(qn ^ kb[m0])) + (double)bh_bias[n * N_TOK + m0];
        double l1 = cf * (double)(64 - 2 * (int)__popcll(qn ^ kb[m1])) + (double)bh_bias[n * N_TOK + m1];
        double l2 = cf * (double)(64 - 2 * (int)__popcll(qn ^ kb[m2])) + (double)bh_bias[n * N_TOK + m2];
        double l3 = -1e300;
        if (m3 < N_TOK)
            l3 = cf * (double)(64 - 2 * (int)__popcll(qn ^ kb[m3])) + (double)bh_bias[n * N_TOK + m3];

        double mx = fmax(fmax(l0, l1), fmax(l2, l3));
#pragma unroll
        for (int off = 32; off > 0; off >>= 1) mx = fmax(mx, __shfl_xor(mx, off, 64));
        double e0 = exp(l0 - mx), e1 = exp(l1 - mx), e2 = exp(l2 - mx);
        double e3 = (m3 < N_TOK) ? exp(l3 - mx) : 0.0;
        double sum = e0 + e1 + e2 + e3;
#pragma unroll
        for (int off = 32; off > 0; off >>= 1) sum += __shfl_xor(sum, off, 64);

        double p0 = S * fmin(rint((e0 / sum) / S), 255.0);
        double p1 = S * fmin(rint((e1 / sum) / S), 255.0);
        double p2 = S * fmin(rint((e2 / sum) / S), 255.0);
        double p3 = S * fmin(rint((e3 / sum) / S), 255.0);

        double acc = 0.0;
        const int d2 = lane;
#pragma unroll
        for (int mm = 0; mm < 64; ++mm) acc = fma(__shfl(p0, mm, 64), (double)vq[mm * 64 + d2], acc);
#pragma unroll
        for (int mm = 0; mm < 64; ++mm) acc = fma(__shfl(p1, mm, 64), (double)vq[(64 + mm) * 64 + d2], acc);
#pragma unroll
        for (int mm = 0; mm < 64; ++mm) acc = fma(__shfl(p2, mm, 64), (double)vq[(128 + mm) * 64 + d2], acc);
#pragma unroll
        for (int mm = 0; mm < 5; ++mm)  acc = fma(__shfl(p3, mm, 64), (double)vq[(192 + mm) * 64 + d2], acc);

        attn_out[((size_t)(b * N_TOK + n)) * C_DIM + h * 64 + d2] = (float)acc;
    }
}

// ---------------------------------------------------------------------------
extern "C" void kernel_launch(void* const* d_in, const int* in_sizes, int n_in,
                              void* d_out, int out_size, void* d_ws, size_t ws_size,
                              hipStream_t stream)
{
    const float* x      = (const float*)d_in[0];
    const float* w_qkv  = (const float*)d_in[1];
    const float* w_proj = (const float*)d_in[2];
    const float* b_proj = (const float*)d_in[3];
    const float* rpb    = (const float*)d_in[4];
    const int*   rel    = (const int*)d_in[5];
    float* out = (float*)d_out;

    char* ws = (char*)d_ws;
    float* qkv     = (float*)ws; ws += (size_t)M_ROWS * QKV_COLS * sizeof(float);  // 116.2 MB
    float* attn_o  = (float*)ws; ws += (size_t)M_ROWS * C_DIM * sizeof(float);     // 38.7 MB
    float* bias_f  = (float*)ws; ws += (size_t)NUM_HEADS * NN * sizeof(float);     // 1.86 MB
    double* sq     = (double*)ws; ws += 768 * sizeof(double);
    double* sk     = (double*)ws; ws += 768 * sizeof(double);
    double* svd    = (double*)ws; ws += 768 * 64 * sizeof(double);
    u64* qbits     = (u64*)ws;   ws += (size_t)768 * N_TOK * sizeof(u64);
    u64* kbits     = (u64*)ws;   ws += (size_t)768 * N_TOK * sizeof(u64);
    int* flag      = (int*)ws;   ws += 256;

    // 0) rel_index dtype probe
    detect_rel64<<<1, 256, 0, stream>>>(rel, flag);

    // 1) QKV = x @ w_qkv^T — 3-way-split 6-term MFMA, error < np's own sgemm noise
    gemm_split6<<<dim3(QKV_COLS / 128, (M_ROWS + 127) / 128), 256, 0, stream>>>(
        x, w_qkv, qkv, M_ROWS, QKV_COLS, C_DIM);

    // 2) per-(b,h) scales (f64), sign bits, v column maxima
    quant_stats_f64<<<768, 256, 0, stream>>>(qkv, sq, sk, qbits, kbits, svd);

    // 3) fp32 bias table per head
    build_bias<<<dim3((NN + 255) / 256, NUM_HEADS), 256, 0, stream>>>(rpb, rel, flag, bias_f);

    // 4) fused attention, f64 decision arithmetic (R5-proven)
    attn_f64<<<768, 256, 0, stream>>>(qkv, sq, sk, qbits, kbits, svd, bias_f, attn_o);

    // 5) out = attn_o @ w_proj^T + b_proj — 2-way-split 4-term MFMA (non-binding)
    gemm_split4_bias<<<dim3(C_DIM / 128, (M_ROWS + 127) / 128), 256, 0, stream>>>(
        attn_o, w_proj, b_proj, out, M_ROWS, C_DIM, C_DIM);
}

// Round 8
// 1181.663 us; speedup vs baseline: 2.9527x; 1.4782x over previous
//
#include <hip/hip_runtime.h>
#include <hip/hip_bf16.h>
#include <math.h>

#define NUM_HEADS 12
#define N_TOK 197
#define C_DIM 768
#define B_SZ 64
#define M_ROWS (B_SZ * N_TOK)     /* 12608 */
#define QKV_COLS (3 * C_DIM)      /* 2304  */
#define NN (N_TOK * N_TOK)        /* 38809 */

typedef __hip_bfloat16 bf16;
typedef __attribute__((ext_vector_type(8))) short short8;
typedef __attribute__((ext_vector_type(4))) float floatx4;
typedef unsigned long long u64;

__device__ __forceinline__ void split2(float x, short& hi, short& lo) {
    bf16 h = __float2bfloat16(x);
    float hf = __bfloat162float(h);
    bf16 l = __float2bfloat16(x - hf);
    hi = __builtin_bit_cast(short, h);
    lo = __builtin_bit_cast(short, l);
}

__device__ __forceinline__ void split3(float x, short& s0, short& s1, short& s2) {
    bf16 h = __float2bfloat16(x);
    float r1 = x - __bfloat162float(h);          // exact
    bf16 m = __float2bfloat16(r1);
    float r2 = r1 - __bfloat162float(m);         // exact
    bf16 l = __float2bfloat16(r2);
    s0 = __builtin_bit_cast(short, h);
    s1 = __builtin_bit_cast(short, m);
    s2 = __builtin_bit_cast(short, l);
}

// ---------------------------------------------------------------------------
// Near-fp32-exact GEMM (QKV path): 3-way bf16 split, 6 MFMA terms; residual
// ~2.6e-7 < np float32 sgemm noise. R7-proven: absmax == f64 oracle.
// ---------------------------------------------------------------------------
__global__ __launch_bounds__(256) void gemm_split6(
    const float* __restrict__ A, const float* __restrict__ B,
    float* __restrict__ C, int M, int N, int K)
{
    __shared__ short8 As[3][512];
    __shared__ short8 Bs[3][512];
    const int t = threadIdx.x;
    const int tile_m = blockIdx.y * 128;
    const int tile_n = blockIdx.x * 128;
    const int wave = t >> 6, lane = t & 63;
    const int quad = lane >> 4, mrow = lane & 15;
    const int wrow = (wave >> 1) * 64, wcol = (wave & 1) * 64;

    floatx4 acc[4][4];
#pragma unroll
    for (int i = 0; i < 4; ++i)
#pragma unroll
        for (int j = 0; j < 4; ++j) acc[i][j] = (floatx4){0.f, 0.f, 0.f, 0.f};

    for (int k0 = 0; k0 < K; k0 += 32) {
        __syncthreads();
#pragma unroll
        for (int s = 0; s < 2; ++s) {
            int idx = s * 256 + t;
            int row = idx >> 2, q = idx & 3;
            {
                int ga = tile_m + row;
                float4 a0 = {0.f, 0.f, 0.f, 0.f}, a1 = {0.f, 0.f, 0.f, 0.f};
                if (ga < M) {
                    const float* p = A + (size_t)ga * K + k0 + q * 8;
                    a0 = *(const float4*)p;
                    a1 = *(const float4*)(p + 4);
                }
                float xs[8] = {a0.x, a0.y, a0.z, a0.w, a1.x, a1.y, a1.z, a1.w};
                short8 v0, v1, v2;
#pragma unroll
                for (int e = 0; e < 8; ++e) {
                    short h, m, l; split3(xs[e], h, m, l);
                    v0[e] = h; v1[e] = m; v2[e] = l;
                }
                As[0][q * 128 + row] = v0;
                As[1][q * 128 + row] = v1;
                As[2][q * 128 + row] = v2;
            }
            {
                int gb = tile_n + row;
                float4 b0 = {0.f, 0.f, 0.f, 0.f}, b1 = {0.f, 0.f, 0.f, 0.f};
                if (gb < N) {
                    const float* p = B + (size_t)gb * K + k0 + q * 8;
                    b0 = *(const float4*)p;
                    b1 = *(const float4*)(p + 4);
                }
                float xs[8] = {b0.x, b0.y, b0.z, b0.w, b1.x, b1.y, b1.z, b1.w};
                short8 v0, v1, v2;
#pragma unroll
                for (int e = 0; e < 8; ++e) {
                    short h, m, l; split3(xs[e], h, m, l);
                    v0[e] = h; v1[e] = m; v2[e] = l;
                }
                Bs[0][q * 128 + row] = v0;
                Bs[1][q * 128 + row] = v1;
                Bs[2][q * 128 + row] = v2;
            }
        }
        __syncthreads();

        short8 af[4], bfr[4];
#pragma unroll
        for (int ta = 0; ta < 3; ++ta) {
#pragma unroll
            for (int i = 0; i < 4; ++i)
                af[i] = As[ta][quad * 128 + wrow + i * 16 + mrow];
            const int ntb = 3 - ta;
#pragma unroll
            for (int tb = 0; tb < 3; ++tb) {
                if (tb >= ntb) break;
#pragma unroll
                for (int j = 0; j < 4; ++j)
                    bfr[j] = Bs[tb][quad * 128 + wcol + j * 16 + mrow];
#pragma unroll
                for (int i = 0; i < 4; ++i)
#pragma unroll
                    for (int j = 0; j < 4; ++j)
                        acc[i][j] = __builtin_amdgcn_mfma_f32_16x16x32_bf16(af[i], bfr[j], acc[i][j], 0, 0, 0);
            }
        }
    }

#pragma unroll
    for (int i = 0; i < 4; ++i)
#pragma unroll
        for (int r = 0; r < 4; ++r) {
            int grow = tile_m + wrow + i * 16 + quad * 4 + r;
            if (grow < M)
#pragma unroll
                for (int j = 0; j < 4; ++j) {
                    int gcol = tile_n + wcol + j * 16 + mrow;
                    C[(size_t)grow * N + gcol] = acc[i][j][r];
                }
        }
}

// ---------------------------------------------------------------------------
// Proj GEMM: 2-way split, 4 terms + bias (precision non-binding here, R2==R3).
// ---------------------------------------------------------------------------
__global__ __launch_bounds__(256) void gemm_split4_bias(
    const float* __restrict__ A, const float* __restrict__ B,
    const float* __restrict__ bias, float* __restrict__ C,
    int M, int N, int K)
{
    __shared__ short8 Ah[512], Al[512];
    __shared__ short8 Bh[512], Bl[512];
    const int t = threadIdx.x;
    const int tile_m = blockIdx.y * 128;
    const int tile_n = blockIdx.x * 128;
    const int wave = t >> 6, lane = t & 63;
    const int quad = lane >> 4, mrow = lane & 15;
    const int wrow = (wave >> 1) * 64, wcol = (wave & 1) * 64;

    floatx4 acc[4][4];
#pragma unroll
    for (int i = 0; i < 4; ++i)
#pragma unroll
        for (int j = 0; j < 4; ++j) acc[i][j] = (floatx4){0.f, 0.f, 0.f, 0.f};

    for (int k0 = 0; k0 < K; k0 += 32) {
        __syncthreads();
#pragma unroll
        for (int s = 0; s < 2; ++s) {
            int idx = s * 256 + t;
            int row = idx >> 2, q = idx & 3;
            {
                int ga = tile_m + row;
                float4 a0 = {0.f, 0.f, 0.f, 0.f}, a1 = {0.f, 0.f, 0.f, 0.f};
                if (ga < M) {
                    const float* p = A + (size_t)ga * K + k0 + q * 8;
                    a0 = *(const float4*)p; a1 = *(const float4*)(p + 4);
                }
                float xs[8] = {a0.x, a0.y, a0.z, a0.w, a1.x, a1.y, a1.z, a1.w};
                short8 hi, lo;
#pragma unroll
                for (int e = 0; e < 8; ++e) { short hh, ll; split2(xs[e], hh, ll); hi[e] = hh; lo[e] = ll; }
                Ah[q * 128 + row] = hi; Al[q * 128 + row] = lo;
            }
            {
                int gb = tile_n + row;
                float4 b0 = {0.f, 0.f, 0.f, 0.f}, b1 = {0.f, 0.f, 0.f, 0.f};
                if (gb < N) {
                    const float* p = B + (size_t)gb * K + k0 + q * 8;
                    b0 = *(const float4*)p; b1 = *(const float4*)(p + 4);
                }
                float xs[8] = {b0.x, b0.y, b0.z, b0.w, b1.x, b1.y, b1.z, b1.w};
                short8 hi, lo;
#pragma unroll
                for (int e = 0; e < 8; ++e) { short hh, ll; split2(xs[e], hh, ll); hi[e] = hh; lo[e] = ll; }
                Bh[q * 128 + row] = hi; Bl[q * 128 + row] = lo;
            }
        }
        __syncthreads();
        short8 ah[4], al[4], bh[4], bl[4];
#pragma unroll
        for (int i = 0; i < 4; ++i) {
            ah[i] = Ah[quad * 128 + wrow + i * 16 + mrow];
            al[i] = Al[quad * 128 + wrow + i * 16 + mrow];
        }
#pragma unroll
        for (int j = 0; j < 4; ++j) {
            bh[j] = Bh[quad * 128 + wcol + j * 16 + mrow];
            bl[j] = Bl[quad * 128 + wcol + j * 16 + mrow];
        }
#pragma unroll
        for (int i = 0; i < 4; ++i)
#pragma unroll
            for (int j = 0; j < 4; ++j) {
                acc[i][j] = __builtin_amdgcn_mfma_f32_16x16x32_bf16(al[i], bl[j], acc[i][j], 0, 0, 0);
                acc[i][j] = __builtin_amdgcn_mfma_f32_16x16x32_bf16(al[i], bh[j], acc[i][j], 0, 0, 0);
                acc[i][j] = __builtin_amdgcn_mfma_f32_16x16x32_bf16(ah[i], bl[j], acc[i][j], 0, 0, 0);
                acc[i][j] = __builtin_amdgcn_mfma_f32_16x16x32_bf16(ah[i], bh[j], acc[i][j], 0, 0, 0);
            }
    }

#pragma unroll
    for (int i = 0; i < 4; ++i)
#pragma unroll
        for (int r = 0; r < 4; ++r) {
            int grow = tile_m + wrow + i * 16 + quad * 4 + r;
            if (grow < M)
#pragma unroll
                for (int j = 0; j < 4; ++j) {
                    int gcol = tile_n + wcol + j * 16 + mrow;
                    C[(size_t)grow * N + gcol] = acc[i][j][r] + bias[gcol];
                }
        }
}

// ---------------------------------------------------------------------------
// Per-(b,h): s_q, s_k (f64 means — cheap, R5-proven), vmax -> fp32 sv exactly
// as np (127.f/(m+1e-6f)), packed q/k sign bits.
// ---------------------------------------------------------------------------
__global__ __launch_bounds__(256) void quant_stats(
    const float* __restrict__ qkv, float* __restrict__ sqf, float* __restrict__ skf,
    u64* __restrict__ qbits, u64* __restrict__ kbits, float* __restrict__ svf)
{
    const int bh = blockIdx.x;
    const int b = bh / NUM_HEADS, h = bh % NUM_HEADS;
    const int t = threadIdx.x;
    const size_t base = (size_t)b * N_TOK * QKV_COLS + h * 64;
    __shared__ double red[256];
    __shared__ float redf[256];

    const int d = t & 63;
    double aq = 0.0, ak = 0.0;
    for (int i = t; i < N_TOK * 64; i += 256) {
        int n = i >> 6;
        size_t off = base + (size_t)n * QKV_COLS + d;
        aq += (double)fabsf(qkv[off]);
        ak += (double)fabsf(qkv[off + C_DIM]);
    }
    red[t] = aq; __syncthreads();
    for (int s = 128; s > 0; s >>= 1) { if (t < s) red[t] += red[t + s]; __syncthreads(); }
    if (t == 0) sqf[bh] = (float)(red[0] / 12608.0);
    __syncthreads();
    red[t] = ak; __syncthreads();
    for (int s = 128; s > 0; s >>= 1) { if (t < s) red[t] += red[t + s]; __syncthreads(); }
    if (t == 0) skf[bh] = (float)(red[0] / 12608.0);
    __syncthreads();

    float vm = 0.f;
    for (int n = (t >> 6); n < N_TOK; n += 4)
        vm = fmaxf(vm, fabsf(qkv[base + (size_t)n * QKV_COLS + 2 * C_DIM + d]));
    redf[t] = vm; __syncthreads();
    if (t < 64) {
        float m4 = fmaxf(fmaxf(redf[t], redf[t + 64]), fmaxf(redf[t + 128], redf[t + 192]));
        svf[bh * 64 + t] = 127.0f / (m4 + 1e-6f);   // np float32 semantics
    }

    const int wave = t >> 6, lane = t & 63;
    for (int n = wave; n < N_TOK; n += 4) {
        size_t off = base + (size_t)n * QKV_COLS + lane;
        u64 bq = __ballot(qkv[off] >= 0.f);
        u64 bk = __ballot(qkv[off + C_DIM] >= 0.f);
        if (lane == 0) { qbits[bh * N_TOK + n] = bq; kbits[bh * N_TOK + n] = bk; }
    }
}

__global__ void detect_rel64(const int* __restrict__ rel, int* __restrict__ flag)
{
    __shared__ int nz;
    if (threadIdx.x == 0) nz = 0;
    __syncthreads();
    int local = 0;
    for (int i = threadIdx.x; i < NN / 2; i += 256)
        if (rel[2 * i + 1] != 0) local = 1;
    if (local) atomicOr(&nz, 1);
    __syncthreads();
    if (threadIdx.x == 0) flag[0] = (nz == 0) ? 1 : 0;
}

__global__ void build_bias(const float* __restrict__ rpb, const int* __restrict__ rel,
                           const int* __restrict__ flag, float* __restrict__ bias_f)
{
    int nm = blockIdx.x * 256 + threadIdx.x;
    int h = blockIdx.y;
    if (nm < NN) {
        int idx = flag[0] ? rel[2 * nm] : rel[nm];
        bias_f[(size_t)h * NN + nm] = rpb[idx * NUM_HEADS + h];
    }
}

// ---------------------------------------------------------------------------
// Fused attention, fp32 arithmetic (R2-proven == f64 given same GEMM inputs).
// v-quant decisions mimic np float32 bit-exactly: rintf(v*sv)/(sv+1e-6f).
// ---------------------------------------------------------------------------
__global__ __launch_bounds__(256) void attn_f32(
    const float* __restrict__ qkv, const float* __restrict__ sqf, const float* __restrict__ skf,
    const u64* __restrict__ qbits, const u64* __restrict__ kbits,
    const float* __restrict__ svf, const float* __restrict__ bias_f,
    float* __restrict__ attn_out)
{
    const int bh = blockIdx.x;
    const int b = bh / NUM_HEADS, h = bh % NUM_HEADS;
    const int t = threadIdx.x;
    const int wave = t >> 6, lane = t & 63;

    __shared__ float vq[N_TOK * 64];   // 50.4 KB
    __shared__ u64 qb[N_TOK], kb[N_TOK];

    const size_t vbase = (size_t)b * N_TOK * QKV_COLS + 2 * C_DIM + h * 64;
    const float sv = svf[bh * 64 + (t & 63)];
    const float inv_sv = sv + 1e-6f;
    for (int i = t; i < N_TOK * 64; i += 256) {
        int n = i >> 6;
        float v = qkv[vbase + (size_t)n * QKV_COLS + (i & 63)];
        vq[i] = rintf(v * sv) / inv_sv;   // np float32 op-sequence
    }
    for (int i = t; i < N_TOK; i += 256) {
        qb[i] = qbits[bh * N_TOK + i];
        kb[i] = kbits[bh * N_TOK + i];
    }
    __syncthreads();

    const float cf = sqf[bh] * skf[bh] * 0.125f;
    const float* bh_bias = bias_f + (size_t)h * NN;
    const float qs = 1.0f / 255.0f;

    for (int n = wave; n < N_TOK; n += 4) {
        const u64 qn = qb[n];
        int m0 = lane, m1 = 64 + lane, m2 = 128 + lane, m3 = 192 + lane;
        float l0 = cf * (float)(64 - 2 * (int)__popcll(qn ^ kb[m0])) + bh_bias[n * N_TOK + m0];
        float l1 = cf * (float)(64 - 2 * (int)__popcll(qn ^ kb[m1])) + bh_bias[n * N_TOK + m1];
        float l2 = cf * (float)(64 - 2 * (int)__popcll(qn ^ kb[m2])) + bh_bias[n * N_TOK + m2];
        float l3 = -1e30f;
        if (m3 < N_TOK)
            l3 = cf * (float)(64 - 2 * (int)__popcll(qn ^ kb[m3])) + bh_bias[n * N_TOK + m3];

        float mx = fmaxf(fmaxf(l0, l1), fmaxf(l2, l3));
#pragma unroll
        for (int off = 32; off > 0; off >>= 1) mx = fmaxf(mx, __shfl_xor(mx, off, 64));
        float e0 = expf(l0 - mx), e1 = expf(l1 - mx), e2 = expf(l2 - mx);
        float e3 = (m3 < N_TOK) ? expf(l3 - mx) : 0.f;
        float sum = e0 + e1 + e2 + e3;
#pragma unroll
        for (int off = 32; off > 0; off >>= 1) sum += __shfl_xor(sum, off, 64);
        float inv = 1.0f / sum;
        float p0 = qs * fminf(rintf((e0 * inv) / qs), 255.f);
        float p1 = qs * fminf(rintf((e1 * inv) / qs), 255.f);
        float p2 = qs * fminf(rintf((e2 * inv) / qs), 255.f);
        float p3 = qs * fminf(rintf((e3 * inv) / qs), 255.f);

        // P @ Vq with 2 interleaved accumulators per group for ILP
        const int d2 = lane;
        float accA = 0.f, accB = 0.f;
#pragma unroll
        for (int mm = 0; mm < 64; mm += 2) {
            accA += __shfl(p0, mm, 64)     * vq[mm * 64 + d2];
            accB += __shfl(p0, mm + 1, 64) * vq[(mm + 1) * 64 + d2];
        }
#pragma unroll
        for (int mm = 0; mm < 64; mm += 2) {
            accA += __shfl(p1, mm, 64)     * vq[(64 + mm) * 64 + d2];
            accB += __shfl(p1, mm + 1, 64) * vq[(64 + mm + 1) * 64 + d2];
        }
#pragma unroll
        for (int mm = 0; mm < 64; mm += 2) {
            accA += __shfl(p2, mm, 64)     * vq[(128 + mm) * 64 + d2];
            accB += __shfl(p2, mm + 1, 64) * vq[(128 + mm + 1) * 64 + d2];
        }
#pragma unroll
        for (int mm = 0; mm < 5; ++mm)
            accA += __shfl(p3, mm, 64) * vq[(192 + mm) * 64 + d2];

        attn_out[((size_t)(b * N_TOK + n)) * C_DIM + h * 64 + d2] = accA + accB;
    }
}

// ---------------------------------------------------------------------------
extern "C" void kernel_launch(void* const* d_in, const int* in_sizes, int n_in,
                              void* d_out, int out_size, void* d_ws, size_t ws_size,
                              hipStream_t stream)
{
    const float* x      = (const float*)d_in[0];
    const float* w_qkv  = (const float*)d_in[1];
    const float* w_proj = (const float*)d_in[2];
    const float* b_proj = (const float*)d_in[3];
    const float* rpb    = (const float*)d_in[4];
    const int*   rel    = (const int*)d_in[5];
    float* out = (float*)d_out;

    char* ws = (char*)d_ws;
    float* qkv     = (float*)ws; ws += (size_t)M_ROWS * QKV_COLS * sizeof(float);  // 116.2 MB
    float* attn_o  = (float*)ws; ws += (size_t)M_ROWS * C_DIM * sizeof(float);     // 38.7 MB
    float* bias_f  = (float*)ws; ws += (size_t)NUM_HEADS * NN * sizeof(float);     // 1.86 MB
    float* sqf     = (float*)ws; ws += 768 * sizeof(float);
    float* skf     = (float*)ws; ws += 768 * sizeof(float);
    float* svf     = (float*)ws; ws += 768 * 64 * sizeof(float);
    u64* qbits     = (u64*)ws;   ws += (size_t)768 * N_TOK * sizeof(u64);
    u64* kbits     = (u64*)ws;   ws += (size_t)768 * N_TOK * sizeof(u64);
    int* flag      = (int*)ws;   ws += 256;

    detect_rel64<<<1, 256, 0, stream>>>(rel, flag);

    gemm_split6<<<dim3(QKV_COLS / 128, (M_ROWS + 127) / 128), 256, 0, stream>>>(
        x, w_qkv, qkv, M_ROWS, QKV_COLS, C_DIM);

    quant_stats<<<768, 256, 0, stream>>>(qkv, sqf, skf, qbits, kbits, svf);

    build_bias<<<dim3((NN + 255) / 256, NUM_HEADS), 256, 0, stream>>>(rpb, rel, flag, bias_f);

    attn_f32<<<768, 256, 0, stream>>>(qkv, sqf, skf, qbits, kbits, svf, bias_f, attn_o);

    gemm_split4_bias<<<dim3(C_DIM / 128, (M_ROWS + 127) / 128), 256, 0, stream>>>(
        attn_o, w_proj, b_proj, out, M_ROWS, C_DIM, C_DIM);
}

// Round 9
// 647.956 us; speedup vs baseline: 5.3849x; 1.8237x over previous
//
#include <hip/hip_runtime.h>
#include <hip/hip_bf16.h>
#include <math.h>

#define NUM_HEADS 12
#define N_TOK 197
#define C_DIM 768
#define B_SZ 64
#define M_ROWS (B_SZ * N_TOK)     /* 12608 */
#define QKV_COLS (3 * C_DIM)      /* 2304  */
#define NN (N_TOK * N_TOK)        /* 38809 */
#define VT_PITCH 232              /* bf16 units; 464B row = 29*16B, odd-ish bank step */

typedef __hip_bfloat16 bf16;
typedef __attribute__((ext_vector_type(8))) short short8;
typedef __attribute__((ext_vector_type(4))) float floatx4;
typedef unsigned long long u64;

__device__ __forceinline__ void split2(float x, short& hi, short& lo) {
    bf16 h = __float2bfloat16(x);
    float hf = __bfloat162float(h);
    bf16 l = __float2bfloat16(x - hf);
    hi = __builtin_bit_cast(short, h);
    lo = __builtin_bit_cast(short, l);
}

__device__ __forceinline__ void split3(float x, short& s0, short& s1, short& s2) {
    bf16 h = __float2bfloat16(x);
    float r1 = x - __bfloat162float(h);          // exact
    bf16 m = __float2bfloat16(r1);
    float r2 = r1 - __bfloat162float(m);         // exact
    bf16 l = __float2bfloat16(r2);
    s0 = __builtin_bit_cast(short, h);
    s1 = __builtin_bit_cast(short, m);
    s2 = __builtin_bit_cast(short, l);
}

// ---------------------------------------------------------------------------
// Near-fp32-exact GEMM (QKV path): 3-way bf16 split, 6 MFMA terms; residual
// ~2.6e-7 < np float32 sgemm noise. R7-proven: absmax == f64 oracle.
// ---------------------------------------------------------------------------
__global__ __launch_bounds__(256) void gemm_split6(
    const float* __restrict__ A, const float* __restrict__ B,
    float* __restrict__ C, int M, int N, int K)
{
    __shared__ short8 As[3][512];
    __shared__ short8 Bs[3][512];
    const int t = threadIdx.x;
    const int tile_m = blockIdx.y * 128;
    const int tile_n = blockIdx.x * 128;
    const int wave = t >> 6, lane = t & 63;
    const int quad = lane >> 4, mrow = lane & 15;
    const int wrow = (wave >> 1) * 64, wcol = (wave & 1) * 64;

    floatx4 acc[4][4];
#pragma unroll
    for (int i = 0; i < 4; ++i)
#pragma unroll
        for (int j = 0; j < 4; ++j) acc[i][j] = (floatx4){0.f, 0.f, 0.f, 0.f};

    for (int k0 = 0; k0 < K; k0 += 32) {
        __syncthreads();
#pragma unroll
        for (int s = 0; s < 2; ++s) {
            int idx = s * 256 + t;
            int row = idx >> 2, q = idx & 3;
            {
                int ga = tile_m + row;
                float4 a0 = {0.f, 0.f, 0.f, 0.f}, a1 = {0.f, 0.f, 0.f, 0.f};
                if (ga < M) {
                    const float* p = A + (size_t)ga * K + k0 + q * 8;
                    a0 = *(const float4*)p;
                    a1 = *(const float4*)(p + 4);
                }
                float xs[8] = {a0.x, a0.y, a0.z, a0.w, a1.x, a1.y, a1.z, a1.w};
                short8 v0, v1, v2;
#pragma unroll
                for (int e = 0; e < 8; ++e) {
                    short h, m, l; split3(xs[e], h, m, l);
                    v0[e] = h; v1[e] = m; v2[e] = l;
                }
                As[0][q * 128 + row] = v0;
                As[1][q * 128 + row] = v1;
                As[2][q * 128 + row] = v2;
            }
            {
                int gb = tile_n + row;
                float4 b0 = {0.f, 0.f, 0.f, 0.f}, b1 = {0.f, 0.f, 0.f, 0.f};
                if (gb < N) {
                    const float* p = B + (size_t)gb * K + k0 + q * 8;
                    b0 = *(const float4*)p;
                    b1 = *(const float4*)(p + 4);
                }
                float xs[8] = {b0.x, b0.y, b0.z, b0.w, b1.x, b1.y, b1.z, b1.w};
                short8 v0, v1, v2;
#pragma unroll
                for (int e = 0; e < 8; ++e) {
                    short h, m, l; split3(xs[e], h, m, l);
                    v0[e] = h; v1[e] = m; v2[e] = l;
                }
                Bs[0][q * 128 + row] = v0;
                Bs[1][q * 128 + row] = v1;
                Bs[2][q * 128 + row] = v2;
            }
        }
        __syncthreads();

        short8 af[4], bfr[4];
#pragma unroll
        for (int ta = 0; ta < 3; ++ta) {
#pragma unroll
            for (int i = 0; i < 4; ++i)
                af[i] = As[ta][quad * 128 + wrow + i * 16 + mrow];
            const int ntb = 3 - ta;
#pragma unroll
            for (int tb = 0; tb < 3; ++tb) {
                if (tb >= ntb) break;
#pragma unroll
                for (int j = 0; j < 4; ++j)
                    bfr[j] = Bs[tb][quad * 128 + wcol + j * 16 + mrow];
#pragma unroll
                for (int i = 0; i < 4; ++i)
#pragma unroll
                    for (int j = 0; j < 4; ++j)
                        acc[i][j] = __builtin_amdgcn_mfma_f32_16x16x32_bf16(af[i], bfr[j], acc[i][j], 0, 0, 0);
            }
        }
    }

#pragma unroll
    for (int i = 0; i < 4; ++i)
#pragma unroll
        for (int r = 0; r < 4; ++r) {
            int grow = tile_m + wrow + i * 16 + quad * 4 + r;
            if (grow < M)
#pragma unroll
                for (int j = 0; j < 4; ++j) {
                    int gcol = tile_n + wcol + j * 16 + mrow;
                    C[(size_t)grow * N + gcol] = acc[i][j][r];
                }
        }
}

// ---------------------------------------------------------------------------
// Proj GEMM: 2-way split, 4 terms + bias (precision non-binding here, R2==R3).
// ---------------------------------------------------------------------------
__global__ __launch_bounds__(256) void gemm_split4_bias(
    const float* __restrict__ A, const float* __restrict__ B,
    const float* __restrict__ bias, float* __restrict__ C,
    int M, int N, int K)
{
    __shared__ short8 Ah[512], Al[512];
    __shared__ short8 Bh[512], Bl[512];
    const int t = threadIdx.x;
    const int tile_m = blockIdx.y * 128;
    const int tile_n = blockIdx.x * 128;
    const int wave = t >> 6, lane = t & 63;
    const int quad = lane >> 4, mrow = lane & 15;
    const int wrow = (wave >> 1) * 64, wcol = (wave & 1) * 64;

    floatx4 acc[4][4];
#pragma unroll
    for (int i = 0; i < 4; ++i)
#pragma unroll
        for (int j = 0; j < 4; ++j) acc[i][j] = (floatx4){0.f, 0.f, 0.f, 0.f};

    for (int k0 = 0; k0 < K; k0 += 32) {
        __syncthreads();
#pragma unroll
        for (int s = 0; s < 2; ++s) {
            int idx = s * 256 + t;
            int row = idx >> 2, q = idx & 3;
            {
                int ga = tile_m + row;
                float4 a0 = {0.f, 0.f, 0.f, 0.f}, a1 = {0.f, 0.f, 0.f, 0.f};
                if (ga < M) {
                    const float* p = A + (size_t)ga * K + k0 + q * 8;
                    a0 = *(const float4*)p; a1 = *(const float4*)(p + 4);
                }
                float xs[8] = {a0.x, a0.y, a0.z, a0.w, a1.x, a1.y, a1.z, a1.w};
                short8 hi, lo;
#pragma unroll
                for (int e = 0; e < 8; ++e) { short hh, ll; split2(xs[e], hh, ll); hi[e] = hh; lo[e] = ll; }
                Ah[q * 128 + row] = hi; Al[q * 128 + row] = lo;
            }
            {
                int gb = tile_n + row;
                float4 b0 = {0.f, 0.f, 0.f, 0.f}, b1 = {0.f, 0.f, 0.f, 0.f};
                if (gb < N) {
                    const float* p = B + (size_t)gb * K + k0 + q * 8;
                    b0 = *(const float4*)p; b1 = *(const float4*)(p + 4);
                }
                float xs[8] = {b0.x, b0.y, b0.z, b0.w, b1.x, b1.y, b1.z, b1.w};
                short8 hi, lo;
#pragma unroll
                for (int e = 0; e < 8; ++e) { short hh, ll; split2(xs[e], hh, ll); hi[e] = hh; lo[e] = ll; }
                Bh[q * 128 + row] = hi; Bl[q * 128 + row] = lo;
            }
        }
        __syncthreads();
        short8 ah[4], al[4], bh[4], bl[4];
#pragma unroll
        for (int i = 0; i < 4; ++i) {
            ah[i] = Ah[quad * 128 + wrow + i * 16 + mrow];
            al[i] = Al[quad * 128 + wrow + i * 16 + mrow];
        }
#pragma unroll
        for (int j = 0; j < 4; ++j) {
            bh[j] = Bh[quad * 128 + wcol + j * 16 + mrow];
            bl[j] = Bl[quad * 128 + wcol + j * 16 + mrow];
        }
#pragma unroll
        for (int i = 0; i < 4; ++i)
#pragma unroll
            for (int j = 0; j < 4; ++j) {
                acc[i][j] = __builtin_amdgcn_mfma_f32_16x16x32_bf16(al[i], bl[j], acc[i][j], 0, 0, 0);
                acc[i][j] = __builtin_amdgcn_mfma_f32_16x16x32_bf16(al[i], bh[j], acc[i][j], 0, 0, 0);
                acc[i][j] = __builtin_amdgcn_mfma_f32_16x16x32_bf16(ah[i], bl[j], acc[i][j], 0, 0, 0);
                acc[i][j] = __builtin_amdgcn_mfma_f32_16x16x32_bf16(ah[i], bh[j], acc[i][j], 0, 0, 0);
            }
    }

#pragma unroll
    for (int i = 0; i < 4; ++i)
#pragma unroll
        for (int r = 0; r < 4; ++r) {
            int grow = tile_m + wrow + i * 16 + quad * 4 + r;
            if (grow < M)
#pragma unroll
                for (int j = 0; j < 4; ++j) {
                    int gcol = tile_n + wcol + j * 16 + mrow;
                    C[(size_t)grow * N + gcol] = acc[i][j][r] + bias[gcol];
                }
        }
}

// ---------------------------------------------------------------------------
// Per-(b,h): s_q, s_k (f64 means), sv = 127.f/(m+1e-6f) np-exact, sign bits.
// ---------------------------------------------------------------------------
__global__ __launch_bounds__(256) void quant_stats(
    const float* __restrict__ qkv, float* __restrict__ sqf, float* __restrict__ skf,
    u64* __restrict__ qbits, u64* __restrict__ kbits, float* __restrict__ svf)
{
    const int bh = blockIdx.x;
    const int b = bh / NUM_HEADS, h = bh % NUM_HEADS;
    const int t = threadIdx.x;
    const size_t base = (size_t)b * N_TOK * QKV_COLS + h * 64;
    __shared__ double red[256];
    __shared__ float redf[256];

    const int d = t & 63;
    double aq = 0.0, ak = 0.0;
    for (int i = t; i < N_TOK * 64; i += 256) {
        int n = i >> 6;
        size_t off = base + (size_t)n * QKV_COLS + d;
        aq += (double)fabsf(qkv[off]);
        ak += (double)fabsf(qkv[off + C_DIM]);
    }
    red[t] = aq; __syncthreads();
    for (int s = 128; s > 0; s >>= 1) { if (t < s) red[t] += red[t + s]; __syncthreads(); }
    if (t == 0) sqf[bh] = (float)(red[0] / 12608.0);
    __syncthreads();
    red[t] = ak; __syncthreads();
    for (int s = 128; s > 0; s >>= 1) { if (t < s) red[t] += red[t + s]; __syncthreads(); }
    if (t == 0) skf[bh] = (float)(red[0] / 12608.0);
    __syncthreads();

    float vm = 0.f;
    for (int n = (t >> 6); n < N_TOK; n += 4)
        vm = fmaxf(vm, fabsf(qkv[base + (size_t)n * QKV_COLS + 2 * C_DIM + d]));
    redf[t] = vm; __syncthreads();
    if (t < 64) {
        float m4 = fmaxf(fmaxf(redf[t], redf[t + 64]), fmaxf(redf[t + 128], redf[t + 192]));
        svf[bh * 64 + t] = 127.0f / (m4 + 1e-6f);
    }

    const int wave = t >> 6, lane = t & 63;
    for (int n = wave; n < N_TOK; n += 4) {
        size_t off = base + (size_t)n * QKV_COLS + lane;
        u64 bq = __ballot(qkv[off] >= 0.f);
        u64 bk = __ballot(qkv[off + C_DIM] >= 0.f);
        if (lane == 0) { qbits[bh * N_TOK + n] = bq; kbits[bh * N_TOK + n] = bk; }
    }
}

__global__ void detect_rel64(const int* __restrict__ rel, int* __restrict__ flag)
{
    __shared__ int nz;
    if (threadIdx.x == 0) nz = 0;
    __syncthreads();
    int local = 0;
    for (int i = threadIdx.x; i < NN / 2; i += 256)
        if (rel[2 * i + 1] != 0) local = 1;
    if (local) atomicOr(&nz, 1);
    __syncthreads();
    if (threadIdx.x == 0) flag[0] = (nz == 0) ? 1 : 0;
}

__global__ void build_bias(const float* __restrict__ rpb, const int* __restrict__ rel,
                           const int* __restrict__ flag, float* __restrict__ bias_f)
{
    int nm = blockIdx.x * 256 + threadIdx.x;
    int h = blockIdx.y;
    if (nm < NN) {
        int idx = flag[0] ? rel[2 * nm] : rel[nm];
        bias_f[(size_t)h * NN + nm] = rpb[idx * NUM_HEADS + h];
    }
}

// ---------------------------------------------------------------------------
// Fused attention with MFMA P@V. Decision arithmetic identical to R8 (fp32).
// P_int (0..255, exact in bf16) strip in LDS (dbuf); Vq 2-way split bf16,
// transposed [d][m] pitch 232; B-fragments preloaded; attn_o = (1/255)*acc.
// ---------------------------------------------------------------------------
__global__ __launch_bounds__(256) void attn_mfma(
    const float* __restrict__ qkv, const float* __restrict__ sqf, const float* __restrict__ skf,
    const u64* __restrict__ qbits, const u64* __restrict__ kbits,
    const float* __restrict__ svf, const float* __restrict__ bias_f,
    float* __restrict__ attn_out)
{
    const int bh = blockIdx.x;
    const int b = bh / NUM_HEADS, h = bh % NUM_HEADS;
    const int t = threadIdx.x;
    const int wave = t >> 6, lane = t & 63;
    const int quad = lane >> 4, mrow = lane & 15;

    __shared__ __align__(16) short vth[64 * VT_PITCH];   // 29696 B
    __shared__ __align__(16) short vtl[64 * VT_PITCH];   // 29696 B
    __shared__ __align__(16) short pbuf[2][16 * VT_PITCH]; // 14848 B
    __shared__ u64 qb[N_TOK], kb[N_TOK];                 // 3152 B

    for (int i = t; i < N_TOK; i += 256) {
        qb[i] = qbits[bh * N_TOK + i];
        kb[i] = kbits[bh * N_TOK + i];
    }

    // V: load, np-exact fp32 quantize, 2-way bf16 split, transposed store.
    const size_t vbase = (size_t)b * N_TOK * QKV_COLS + 2 * C_DIM + h * 64;
    const int d0 = t & 63;
    const float sv = svf[bh * 64 + d0];
    const float inv_sv = sv + 1e-6f;
    for (int i = t; i < N_TOK * 64; i += 256) {
        int n = i >> 6;
        float v = qkv[vbase + (size_t)n * QKV_COLS + d0];
        float vqf = rintf(v * sv) / inv_sv;     // np float32 op-sequence (R8-proven)
        short hh, ll; split2(vqf, hh, ll);
        vth[d0 * VT_PITCH + n] = hh;
        vtl[d0 * VT_PITCH + n] = ll;
    }
    for (int i = t; i < 64 * (VT_PITCH - N_TOK); i += 256) {  // zero k-pads
        int d = i / (VT_PITCH - N_TOK), n = N_TOK + i % (VT_PITCH - N_TOK);
        vth[d * VT_PITCH + n] = 0;
        vtl[d * VT_PITCH + n] = 0;
    }
    __syncthreads();

    // Preload B-fragments: B[n=d_local][k] from vt[(ct*16+mrow)][ktile*32+quad*8..+7]
    const int ct = wave;   // 16-col tile of d handled by this wave
    short8 bfh[7], bfl[7];
#pragma unroll
    for (int kt = 0; kt < 7; ++kt) {
        int off = (ct * 16 + mrow) * VT_PITCH + kt * 32 + quad * 8;
        bfh[kt] = *(const short8*)&vth[off];
        bfl[kt] = *(const short8*)&vtl[off];
    }

    const float cf = sqf[bh] * skf[bh] * 0.125f;
    const float* bh_bias = bias_f + (size_t)h * NN;
    const float qs = 1.0f / 255.0f;

    // P-strip compute: 4 rows per wave; arithmetic identical to R8.
    auto computeP = [&](int strip, int buf) {
        short* pb = &pbuf[buf][0];
#pragma unroll
        for (int rr = 0; rr < 4; ++rr) {
            int nl = wave * 4 + rr;
            int n = strip * 16 + nl;
            short* prow = pb + nl * VT_PITCH;
            int m0 = lane, m1 = 64 + lane, m2 = 128 + lane, m3 = 192 + lane;
            if (n < N_TOK) {
                const u64 qn = qb[n];
                const float* brow = bh_bias + (size_t)n * N_TOK;
                float l0 = cf * (float)(64 - 2 * (int)__popcll(qn ^ kb[m0])) + brow[m0];
                float l1 = cf * (float)(64 - 2 * (int)__popcll(qn ^ kb[m1])) + brow[m1];
                float l2 = cf * (float)(64 - 2 * (int)__popcll(qn ^ kb[m2])) + brow[m2];
                float l3 = -1e30f;
                if (m3 < N_TOK)
                    l3 = cf * (float)(64 - 2 * (int)__popcll(qn ^ kb[m3])) + brow[m3];
                float mx = fmaxf(fmaxf(l0, l1), fmaxf(l2, l3));
#pragma unroll
                for (int off = 32; off > 0; off >>= 1) mx = fmaxf(mx, __shfl_xor(mx, off, 64));
                float e0 = expf(l0 - mx), e1 = expf(l1 - mx), e2 = expf(l2 - mx);
                float e3 = (m3 < N_TOK) ? expf(l3 - mx) : 0.f;
                float sum = e0 + e1 + e2 + e3;
#pragma unroll
                for (int off = 32; off > 0; off >>= 1) sum += __shfl_xor(sum, off, 64);
                float inv = 1.0f / sum;
                float p0 = fminf(rintf((e0 * inv) / qs), 255.f);   // P_int, exact in bf16
                float p1 = fminf(rintf((e1 * inv) / qs), 255.f);
                float p2 = fminf(rintf((e2 * inv) / qs), 255.f);
                float p3 = fminf(rintf((e3 * inv) / qs), 255.f);   // 0 when e3==0
                prow[m0] = __builtin_bit_cast(short, __float2bfloat16(p0));
                prow[m1] = __builtin_bit_cast(short, __float2bfloat16(p1));
                prow[m2] = __builtin_bit_cast(short, __float2bfloat16(p2));
                if (m3 < VT_PITCH)
                    prow[m3] = __builtin_bit_cast(short, __float2bfloat16(p3));
            } else {
                prow[m0] = 0; prow[m1] = 0; prow[m2] = 0;
                if (m3 < VT_PITCH) prow[m3] = 0;
            }
        }
    };

    computeP(0, 0);
    __syncthreads();

    for (int strip = 0; strip < 13; ++strip) {
        if (strip + 1 < 13) computeP(strip + 1, (strip + 1) & 1);

        const short* pb = &pbuf[strip & 1][0];
        floatx4 acc = (floatx4){0.f, 0.f, 0.f, 0.f};
#pragma unroll
        for (int kt = 0; kt < 7; ++kt) {
            short8 af = *(const short8*)&pb[mrow * VT_PITCH + kt * 32 + quad * 8];
            acc = __builtin_amdgcn_mfma_f32_16x16x32_bf16(af, bfh[kt], acc, 0, 0, 0);
            acc = __builtin_amdgcn_mfma_f32_16x16x32_bf16(af, bfl[kt], acc, 0, 0, 0);
        }
#pragma unroll
        for (int r = 0; r < 4; ++r) {
            int n = strip * 16 + quad * 4 + r;
            if (n < N_TOK)
                attn_out[((size_t)(b * N_TOK + n)) * C_DIM + h * 64 + ct * 16 + mrow] = qs * acc[r];
        }
        __syncthreads();
    }
}

// ---------------------------------------------------------------------------
extern "C" void kernel_launch(void* const* d_in, const int* in_sizes, int n_in,
                              void* d_out, int out_size, void* d_ws, size_t ws_size,
                              hipStream_t stream)
{
    const float* x      = (const float*)d_in[0];
    const float* w_qkv  = (const float*)d_in[1];
    const float* w_proj = (const float*)d_in[2];
    const float* b_proj = (const float*)d_in[3];
    const float* rpb    = (const float*)d_in[4];
    const int*   rel    = (const int*)d_in[5];
    float* out = (float*)d_out;

    char* ws = (char*)d_ws;
    float* qkv     = (float*)ws; ws += (size_t)M_ROWS * QKV_COLS * sizeof(float);
    float* attn_o  = (float*)ws; ws += (size_t)M_ROWS * C_DIM * sizeof(float);
    float* bias_f  = (float*)ws; ws += (size_t)NUM_HEADS * NN * sizeof(float);
    float* sqf     = (float*)ws; ws += 768 * sizeof(float);
    float* skf     = (float*)ws; ws += 768 * sizeof(float);
    float* svf     = (float*)ws; ws += 768 * 64 * sizeof(float);
    u64* qbits     = (u64*)ws;   ws += (size_t)768 * N_TOK * sizeof(u64);
    u64* kbits     = (u64*)ws;   ws += (size_t)768 * N_TOK * sizeof(u64);
    int* flag      = (int*)ws;   ws += 256;

    detect_rel64<<<1, 256, 0, stream>>>(rel, flag);

    gemm_split6<<<dim3(QKV_COLS / 128, (M_ROWS + 127) / 128), 256, 0, stream>>>(
        x, w_qkv, qkv, M_ROWS, QKV_COLS, C_DIM);

    quant_stats<<<768, 256, 0, stream>>>(qkv, sqf, skf, qbits, kbits, svf);

    build_bias<<<dim3((NN + 255) / 256, NUM_HEADS), 256, 0, stream>>>(rpb, rel, flag, bias_f);

    attn_mfma<<<768, 256, 0, stream>>>(qkv, sqf, skf, qbits, kbits, svf, bias_f, attn_o);

    gemm_split4_bias<<<dim3(C_DIM / 128, (M_ROWS + 127) / 128), 256, 0, stream>>>(
        attn_o, w_proj, b_proj, out, M_ROWS, C_DIM, C_DIM);
}